// Round 8
// baseline (534.294 us; speedup 1.0000x reference)
//
#include <hip/hip_runtime.h>
#include <hip/hip_bf16.h>
#include <math.h>

#define NROWS 8192
#define DIM 128
#define CS 32                         // column slabs
#define COLS_PER_SLAB (NROWS / CS)    // 256
#define CT_ITERS (COLS_PER_SLAB / 32) // 8

typedef __attribute__((ext_vector_type(8))) short bf16x8;
typedef __attribute__((ext_vector_type(4))) float f32x4;

// ---------------- label histogram (single block, LDS sub-hists, NO global atomics)
// also zeroes losssum
__global__ __launch_bounds__(1024) void k_hist(const int* __restrict__ lab,
                                               int* __restrict__ hist,
                                               float* __restrict__ losssum) {
  __shared__ int sh[16][16];
  const int t = threadIdx.x;
  const int w = t >> 6;
  if ((t & 63) < 16) sh[w][t & 63] = 0;
  __syncthreads();
#pragma unroll
  for (int it = 0; it < NROWS / 1024; ++it)
    atomicAdd(&sh[w][lab[t + it * 1024]], 1);
  __syncthreads();
  if (t < 10) {
    int s = 0;
#pragma unroll
    for (int x = 0; x < 16; ++x) s += sh[x][t];
    hist[t] = s;
  }
  if (t == 10) losssum[0] = 0.f;
}

// ---------------- normalize rows -> bf16 ----------------
__global__ __launch_bounds__(256) void k_norm(const float* __restrict__ f,
                                              __hip_bfloat16* __restrict__ fnb) {
  int wave = threadIdx.x >> 6;
  int lane = threadIdx.x & 63;
  int row = blockIdx.x * 4 + wave;
  const float* src = f + (size_t)row * DIM;
  float v0 = src[lane];
  float v1 = src[lane + 64];
  float ss = v0 * v0 + v1 * v1;
#pragma unroll
  for (int o = 32; o > 0; o >>= 1) ss += __shfl_down(ss, o);
  ss = __shfl(ss, 0);
  float inv = 1.0f / fmaxf(sqrtf(ss), 1e-8f);
  __hip_bfloat16* dst = fnb + (size_t)row * DIM;
  dst[lane] = __float2bfloat16(v0 * inv);
  dst[lane + 64] = __float2bfloat16(v1 * inv);
}

// ---------------- single MFMA pass, LDS-free, epilogue-pipelined ----------------
// 4096 waves: gid -> cs = gid>>7 (col slab of 256), i0 = (gid&127)*64.
// Per ct: issue B loads -> epilogue of PREVIOUS acc (covers L2 latency) -> MFMA.
__global__ __launch_bounds__(256, 4) void k_main(
    const ushort* __restrict__ fnb, const int* __restrict__ lab,
    float* __restrict__ ptot, float* __restrict__ ppos, float* __restrict__ psim) {
  const int lane = threadIdx.x & 63;
  const int g = lane >> 4;      // k-chunk group
  const int li16 = lane & 15;   // row/col within 16-tile
  const int gid = blockIdx.x * 4 + (threadIdx.x >> 6);
  const int cs = gid >> 7;
  const int i0 = (gid & 127) * 64;

  // A fragments: rows i0 + m*16 + li16, k = ks*32 + g*8
  bf16x8 af[4][4];
#pragma unroll
  for (int m = 0; m < 4; ++m) {
    const ushort* arow = fnb + (size_t)(i0 + m * 16 + li16) * DIM + g * 8;
#pragma unroll
    for (int ks = 0; ks < 4; ++ks)
      af[m][ks] = *reinterpret_cast<const bf16x8*>(arow + ks * 32);
  }

  // labels of this thread's C rows: row = i0 + m*16 + g*4 + r
  int lr[4][4];
#pragma unroll
  for (int m = 0; m < 4; ++m)
#pragma unroll
    for (int r = 0; r < 4; ++r)
      lr[m][r] = lab[i0 + m * 16 + g * 4 + r];

  float a_tot[4][4] = {}, a_pos[4][4] = {}, a_sim[4][4] = {};
  f32x4 acc[4][2];
  int lcp[2];

  const int jslab = cs * COLS_PER_SLAB;
#pragma unroll
  for (int ct = 0; ct < CT_ITERS; ++ct) {
    const int jb = jslab + ct * 32;
    const int lc0 = lab[jb + li16];
    const int lc1 = lab[jb + 16 + li16];

    // issue B loads for THIS tile (latency hidden by epilogue below)
    bf16x8 bf[2][4];
#pragma unroll
    for (int n = 0; n < 2; ++n) {
      const ushort* brow = fnb + (size_t)(jb + n * 16 + li16) * DIM + g * 8;
#pragma unroll
      for (int ks = 0; ks < 4; ++ks)
        bf[n][ks] = *reinterpret_cast<const bf16x8*>(brow + ks * 32);
    }

    // epilogue of PREVIOUS tile (VALU work independent of the loads above)
    if (ct > 0) {
#pragma unroll
      for (int n = 0; n < 2; ++n) {
        const int lc = (n == 0) ? lcp[0] : lcp[1];
#pragma unroll
        for (int m = 0; m < 4; ++m)
#pragma unroll
          for (int r = 0; r < 4; ++r) {
            float s = acc[m][n][r];           // cos sim (sim = 2*s)
            float E = __expf(2.0f * s);
            bool pos = (lr[m][r] == lc);
            a_tot[m][r] += E;
            a_pos[m][r] += pos ? E : 0.f;
            a_sim[m][r] += pos ? s : 0.f;
          }
      }
    }

#pragma unroll
    for (int m = 0; m < 4; ++m)
#pragma unroll
      for (int n = 0; n < 2; ++n) acc[m][n] = (f32x4){0.f, 0.f, 0.f, 0.f};

#pragma unroll
    for (int ks = 0; ks < 4; ++ks)
#pragma unroll
      for (int m = 0; m < 4; ++m)
#pragma unroll
        for (int n = 0; n < 2; ++n)
          acc[m][n] = __builtin_amdgcn_mfma_f32_16x16x32_bf16(af[m][ks], bf[n][ks],
                                                              acc[m][n], 0, 0, 0);
    lcp[0] = lc0;
    lcp[1] = lc1;
  }

  // final tile's epilogue
#pragma unroll
  for (int n = 0; n < 2; ++n) {
    const int lc = (n == 0) ? lcp[0] : lcp[1];
#pragma unroll
    for (int m = 0; m < 4; ++m)
#pragma unroll
      for (int r = 0; r < 4; ++r) {
        float s = acc[m][n][r];
        float E = __expf(2.0f * s);
        bool pos = (lr[m][r] == lc);
        a_tot[m][r] += E;
        a_pos[m][r] += pos ? E : 0.f;
        a_sim[m][r] += pos ? s : 0.f;
      }
  }

  // reduce across the 16 lanes (cols) of each row group
#pragma unroll
  for (int m = 0; m < 4; ++m)
#pragma unroll
    for (int r = 0; r < 4; ++r)
#pragma unroll
      for (int off = 8; off > 0; off >>= 1) {
        a_tot[m][r] += __shfl_xor(a_tot[m][r], off);
        a_pos[m][r] += __shfl_xor(a_pos[m][r], off);
        a_sim[m][r] += __shfl_xor(a_sim[m][r], off);
      }

  if (li16 == 0) {
#pragma unroll
    for (int m = 0; m < 4; ++m)
#pragma unroll
      for (int r = 0; r < 4; ++r) {
        int row = i0 + m * 16 + g * 4 + r;
        ptot[(size_t)cs * NROWS + row] = a_tot[m][r];
        ppos[(size_t)cs * NROWS + row] = a_pos[m][r];
        psim[(size_t)cs * NROWS + row] = a_sim[m][r];
      }
  }
}

// ---------------- per-row finalize + global sum ----------------
__global__ __launch_bounds__(1024) void k_rowfinal(
    const float* __restrict__ ptot, const float* __restrict__ ppos,
    const float* __restrict__ psim,
    const int* __restrict__ lab, const int* __restrict__ hist,
    float* __restrict__ losssum) {
  __shared__ float sred[1024];
  int i = blockIdx.x * 1024 + threadIdx.x;
  float st = 0.f, sp = 0.f, sa = 0.f;
#pragma unroll
  for (int cs = 0; cs < CS; ++cs) {
    st += ptot[(size_t)cs * NROWS + i];
    sp += ppos[(size_t)cs * NROWS + i];
    sa += psim[(size_t)cs * NROWS + i];
  }
  float cnt = (float)hist[lab[i]];
  float negtot = st - sp + cnt;  // negatives' E + positives' exp(0)=1 each
  // sum over positives of [log(negtot) + log1p(E/negtot) - sim]
  //   ~= cnt*log(negtot) + posE/negtot - 2*posS
  float li = cnt * logf(negtot) + sp / negtot - 2.f * sa;
  sred[threadIdx.x] = li;
  __syncthreads();
  for (int s2 = 512; s2 > 0; s2 >>= 1) {
    if (threadIdx.x < s2) sred[threadIdx.x] += sred[threadIdx.x + s2];
    __syncthreads();
  }
  if (threadIdx.x == 0) atomicAdd(losssum, sred[0]);
}

// ---------------- output ----------------
__global__ void k_out(const float* __restrict__ losssum, const int* __restrict__ hist,
                      float* __restrict__ out) {
  if (threadIdx.x == 0) {
    double np = 0.0;
    for (int c = 0; c < 10; ++c) np += (double)hist[c] * (double)hist[c];
    out[0] = (float)((double)losssum[0] / np);
  }
}

extern "C" void kernel_launch(void* const* d_in, const int* in_sizes, int n_in,
                              void* d_out, int out_size, void* d_ws, size_t ws_size,
                              hipStream_t stream) {
  const float* feat = (const float*)d_in[0];
  const int* lab = (const int*)d_in[1];
  float* out = (float*)d_out;

  char* ws = (char*)d_ws;
  __hip_bfloat16* fnb = (__hip_bfloat16*)ws;               // 2 MiB
  size_t off = (size_t)NROWS * DIM * 2;
  float* ptot = (float*)(ws + off); off += (size_t)CS * NROWS * 4;   // 1 MiB
  float* ppos = (float*)(ws + off); off += (size_t)CS * NROWS * 4;
  float* psim = (float*)(ws + off); off += (size_t)CS * NROWS * 4;
  int* hist = (int*)(ws + off);     off += 64;
  float* losssum = (float*)(ws + off);

  k_norm<<<NROWS / 4, 256, 0, stream>>>(feat, fnb);
  k_hist<<<1, 1024, 0, stream>>>(lab, hist, losssum);
  k_main<<<1024, 256, 0, stream>>>((const ushort*)fnb, lab, ptot, ppos, psim);
  k_rowfinal<<<NROWS / 1024, 1024, 0, stream>>>(ptot, ppos, psim, lab, hist, losssum);
  k_out<<<1, 64, 0, stream>>>(losssum, hist, out);
}

// Round 9
// 50.927 us; speedup vs baseline: 10.4914x; 10.4914x over previous
//
#include <hip/hip_runtime.h>
#include <hip/hip_bf16.h>
#include <math.h>

#define NROWS 8192
#define DIM 128
#define BM 128                        // rows per block tile
#define BN 128                        // cols per inner tile
#define CS 8                          // column slabs
#define COLS_PER_SLAB (NROWS / CS)    // 1024
#define CT_ITERS (COLS_PER_SLAB / BN) // 8
#define RS (NROWS / BM)               // 64
#define SQRT2 1.41421356237309515f

typedef __attribute__((ext_vector_type(8))) short bf16x8;
typedef __attribute__((ext_vector_type(4))) float f32x4;

// ---------------- normalize rows -> bf16 scaled by sqrt(2)  (acc becomes sim=2*cos)
// block 0 thread 0 zeroes losssum[0]
__global__ __launch_bounds__(256) void k_norm(const float* __restrict__ f,
                                              __hip_bfloat16* __restrict__ fnb,
                                              float* __restrict__ losssum) {
  if (blockIdx.x == 0 && threadIdx.x == 0) losssum[0] = 0.f;
  int wave = threadIdx.x >> 6;
  int lane = threadIdx.x & 63;
  int row = blockIdx.x * 4 + wave;
  const float* src = f + (size_t)row * DIM;
  float v0 = src[lane];
  float v1 = src[lane + 64];
  float ss = v0 * v0 + v1 * v1;
#pragma unroll
  for (int o = 32; o > 0; o >>= 1) ss += __shfl_down(ss, o);
  ss = __shfl(ss, 0);
  float inv = SQRT2 / fmaxf(sqrtf(ss), 1e-8f);
  __hip_bfloat16* dst = fnb + (size_t)row * DIM;
  dst[lane] = __float2bfloat16(v0 * inv);
  dst[lane + 64] = __float2bfloat16(v1 * inv);
}

// ---------------- single MFMA pass ----------------
// 256 threads = 4 waves (2 row-halves x 2 col-halves), per-wave 64x64 C-tile.
// acc = sim = 2*cos.  Per row: totE=sum_all e^sim, posE=sum_pos e^sim, posS=sum_pos sim.
__global__ __launch_bounds__(256, 2) void k_main(
    const ushort* __restrict__ fnb, const int* __restrict__ lab,
    float* __restrict__ ptot, float* __restrict__ ppos, float* __restrict__ psim) {
  __shared__ char lds[BM * 256 + BN * 256];  // A (32KB) + B (32KB), swizzled
  char* Alds = lds;
  char* Blds = lds + BM * 256;

  const int t = threadIdx.x;
  const int lane = t & 63;
  const int w = t >> 6;
  const int wm = w >> 1;    // 0..1 row half
  const int wn = w & 1;     // 0..1 col half
  const int g = lane >> 4;  // 0..3
  const int li16 = lane & 15;
  const int cs = blockIdx.x;
  const int i0 = blockIdx.y * BM;

  // ---- stage A once (rows i0..i0+127), XOR-swizzled ----
  {
    const int4* src = reinterpret_cast<const int4*>(fnb + (size_t)i0 * DIM);
#pragma unroll
    for (int it = 0; it < 8; ++it) {
      int q = t + 256 * it;     // 0..2047 16B-chunks
      int row = q >> 4, c = q & 15;
      int4 v = src[q];
      *reinterpret_cast<int4*>(Alds + row * 256 + ((c << 4) ^ ((row & 7) << 4))) = v;
    }
  }

  // labels of this thread's C rows: row = wm*64 + m*16 + g*4 + r
  int lr[4][4];
#pragma unroll
  for (int m = 0; m < 4; ++m)
#pragma unroll
    for (int r = 0; r < 4; ++r)
      lr[m][r] = lab[i0 + wm * 64 + m * 16 + g * 4 + r];

  float a_tot[4][4] = {}, a_pos[4][4] = {}, a_sim[4][4] = {};

  for (int ct = 0; ct < CT_ITERS; ++ct) {
    const int j0 = cs * COLS_PER_SLAB + ct * BN;
    __syncthreads();  // previous iteration's readers done with Blds
    {
      const int4* src = reinterpret_cast<const int4*>(fnb + (size_t)j0 * DIM);
#pragma unroll
      for (int it = 0; it < 8; ++it) {
        int q = t + 256 * it;
        int row = q >> 4, c = q & 15;
        int4 v = src[q];
        *reinterpret_cast<int4*>(Blds + row * 256 + ((c << 4) ^ ((row & 7) << 4))) = v;
      }
    }
    __syncthreads();

    f32x4 acc[4][4];
#pragma unroll
    for (int m = 0; m < 4; ++m)
#pragma unroll
      for (int n = 0; n < 4; ++n) acc[m][n] = (f32x4){0.f, 0.f, 0.f, 0.f};

#pragma unroll
    for (int ks = 0; ks < 4; ++ks) {
      const int kb = ks * 64 + (g << 4);  // 16B chunk within 256B row
      bf16x8 af[4], bf[4];
#pragma unroll
      for (int m = 0; m < 4; ++m) {
        int r = wm * 64 + m * 16 + li16;
        af[m] = *reinterpret_cast<const bf16x8*>(Alds + r * 256 + (kb ^ ((r & 7) << 4)));
      }
#pragma unroll
      for (int n = 0; n < 4; ++n) {
        int r = wn * 64 + n * 16 + li16;
        bf[n] = *reinterpret_cast<const bf16x8*>(Blds + r * 256 + (kb ^ ((r & 7) << 4)));
      }
#pragma unroll
      for (int m = 0; m < 4; ++m)
#pragma unroll
        for (int n = 0; n < 4; ++n)
          acc[m][n] = __builtin_amdgcn_mfma_f32_16x16x32_bf16(af[m], bf[n], acc[m][n], 0, 0, 0);
    }

    // epilogue: acc IS sim; E = exp(sim)
#pragma unroll
    for (int n = 0; n < 4; ++n) {
      const int lc = lab[j0 + wn * 64 + n * 16 + li16];
#pragma unroll
      for (int m = 0; m < 4; ++m)
#pragma unroll
        for (int r = 0; r < 4; ++r) {
          float s = acc[m][n][r];
          float E = __expf(s);
          bool pos = (lr[m][r] == lc);
          a_tot[m][r] += E;
          a_pos[m][r] += pos ? E : 0.f;
          a_sim[m][r] += pos ? s : 0.f;
        }
    }
  }

  // reduce across the 16 cols held by li16 lanes
#pragma unroll
  for (int m = 0; m < 4; ++m)
#pragma unroll
    for (int r = 0; r < 4; ++r)
#pragma unroll
      for (int off = 8; off > 0; off >>= 1) {
        a_tot[m][r] += __shfl_xor(a_tot[m][r], off);
        a_pos[m][r] += __shfl_xor(a_pos[m][r], off);
        a_sim[m][r] += __shfl_xor(a_sim[m][r], off);
      }

  __syncthreads();  // tiles done; reuse LDS as scratch
  float(*red)[2][3] = reinterpret_cast<float(*)[2][3]>(lds);  // [128][wn][3]
  if (li16 == 0) {
#pragma unroll
    for (int m = 0; m < 4; ++m)
#pragma unroll
      for (int r = 0; r < 4; ++r) {
        int rl = wm * 64 + m * 16 + g * 4 + r;
        red[rl][wn][0] = a_tot[m][r];
        red[rl][wn][1] = a_pos[m][r];
        red[rl][wn][2] = a_sim[m][r];
      }
  }
  __syncthreads();
  if (wn == 0 && li16 == 0) {
#pragma unroll
    for (int m = 0; m < 4; ++m)
#pragma unroll
      for (int r = 0; r < 4; ++r) {
        int rl = wm * 64 + m * 16 + g * 4 + r;
        int row = i0 + rl;
        ptot[(size_t)cs * NROWS + row] = red[rl][0][0] + red[rl][1][0];
        ppos[(size_t)cs * NROWS + row] = red[rl][0][1] + red[rl][1][1];
        psim[(size_t)cs * NROWS + row] = red[rl][0][2] + red[rl][1][2];
      }
  }
}

// ---------------- per-row finalize + global sum (in-LDS hist, 8 blocks) ----------------
__global__ __launch_bounds__(1024) void k_rowfinal(
    const float* __restrict__ ptot, const float* __restrict__ ppos,
    const float* __restrict__ psim, const int* __restrict__ lab,
    float* __restrict__ losssum) {
  __shared__ int sh[16][16];
  __shared__ int hist_s[16];
  __shared__ float sred[1024];
  const int t = threadIdx.x;
  const int w = t >> 6;
  if ((t & 63) < 16) sh[w][t & 63] = 0;
  __syncthreads();
#pragma unroll
  for (int it = 0; it < NROWS / 1024; ++it)
    atomicAdd(&sh[w][lab[t + it * 1024]], 1);
  __syncthreads();
  if (t < 16) {
    int s = 0;
#pragma unroll
    for (int x = 0; x < 16; ++x) s += sh[x][t];
    hist_s[t] = s;
  }
  __syncthreads();

  int i = blockIdx.x * 1024 + t;
  float st = 0.f, sp = 0.f, sa = 0.f;
#pragma unroll
  for (int cs = 0; cs < CS; ++cs) {
    st += ptot[(size_t)cs * NROWS + i];
    sp += ppos[(size_t)cs * NROWS + i];
    sa += psim[(size_t)cs * NROWS + i];
  }
  float cnt = (float)hist_s[lab[i]];
  float negtot = st - sp + cnt;  // negatives' E + positives count (exp(0)=1 each)
  // sum over positives of [log(negtot) + log1p(E/negtot) - sim] ~= cnt*log(negtot)+posE/negtot-posS
  float li = cnt * logf(negtot) + sp / negtot - sa;
  sred[t] = li;
  __syncthreads();
  for (int s2 = 512; s2 > 0; s2 >>= 1) {
    if (t < s2) sred[t] += sred[t + s2];
    __syncthreads();
  }
  if (t == 0) {
    atomicAdd(&losssum[0], sred[0]);
    if (blockIdx.x == 0) {
      int np = 0;
#pragma unroll
      for (int c = 0; c < 10; ++c) np += hist_s[c] * hist_s[c];
      losssum[1] = (float)np;
    }
  }
}

// ---------------- output ----------------
__global__ void k_out(const float* __restrict__ losssum, float* __restrict__ out) {
  if (threadIdx.x == 0) out[0] = losssum[0] / losssum[1];
}

extern "C" void kernel_launch(void* const* d_in, const int* in_sizes, int n_in,
                              void* d_out, int out_size, void* d_ws, size_t ws_size,
                              hipStream_t stream) {
  const float* feat = (const float*)d_in[0];
  const int* lab = (const int*)d_in[1];
  float* out = (float*)d_out;

  char* ws = (char*)d_ws;
  __hip_bfloat16* fnb = (__hip_bfloat16*)ws;               // 2 MiB
  size_t off = (size_t)NROWS * DIM * 2;
  float* ptot = (float*)(ws + off); off += (size_t)CS * NROWS * 4;   // 256 KiB
  float* ppos = (float*)(ws + off); off += (size_t)CS * NROWS * 4;
  float* psim = (float*)(ws + off); off += (size_t)CS * NROWS * 4;
  float* losssum = (float*)(ws + off);

  k_norm<<<NROWS / 4, 256, 0, stream>>>(feat, fnb, losssum);
  dim3 grid(CS, RS);
  k_main<<<grid, 256, 0, stream>>>((const ushort*)fnb, lab, ptot, ppos, psim);
  k_rowfinal<<<NROWS / 1024, 1024, 0, stream>>>(ptot, ppos, psim, lab, losssum);
  k_out<<<1, 64, 0, stream>>>(losssum, out);
}